// Round 1
// baseline (940.584 us; speedup 1.0000x reference)
//
#include <hip/hip_runtime.h>
#include <hip/hip_bf16.h>
#include <math.h>

// Problem constants
#define DD 8
#define NN 256
#define HH 512
#define BB 4096
#define MM 36

enum { EPI_NONE = 0, EPI_SPSIG = 1, EPI_TANH = 2, EPI_GATE = 3 };

__device__ __forceinline__ float softplus_f(float x) {
    return fmaxf(x, 0.f) + log1pf(__expf(-fabsf(x)));
}
__device__ __forceinline__ float sigmoid_f(float x) {
    return 1.f / (1.f + __expf(-x));
}

// Generic tiled GEMM: C[row, col] = EPI( sum_k A[row*lda+k] * W[col*ldw+k] + bias[col] )
// Tile: 128 rows x 64 cols x 16 K. 256 threads, 8x4 micro-tile per thread.
// blockIdx.z batching via aZ/wZ/cZ element offsets (for the per-field diagonal GEMM).
template <int EPI>
__global__ __launch_bounds__(256) void gemm_k(
    const float* __restrict__ A, int lda, int aZ,
    const float* __restrict__ W, int ldw, int wZ,
    const float* __restrict__ bias,
    float* __restrict__ C0, int ldc, int cZ,
    float* __restrict__ C1,              // secondary output (sigmoid) for EPI_SPSIG
    const float* __restrict__ G,         // gate for EPI_GATE: G[(row>>3)*ldc + col]
    int K)
{
    __shared__ float As[16][132];  // [k][row], padded stride 132
    __shared__ float Ws[16][68];   // [k][col], padded stride 68

    const int t = threadIdx.x;
    const int z = blockIdx.z;
    A  += (size_t)z * aZ;
    W  += (size_t)z * wZ;
    C0 += (size_t)z * cZ;

    const int rowTile = blockIdx.x * 128;
    const int colTile = blockIdx.y * 64;
    const int tx = t & 15;        // col group
    const int tyy = t >> 4;       // row group
    const int r0 = tyy * 8;
    const int c0 = tx * 4;

    float acc[8][4];
#pragma unroll
    for (int i = 0; i < 8; ++i)
#pragma unroll
        for (int j = 0; j < 4; ++j) acc[i][j] = 0.f;

    const int lrow = t >> 2;      // 0..63
    const int lq = t & 3;         // quad within 16-float row

    for (int k0 = 0; k0 < K; k0 += 16) {
        // Load A tile (128x16): 2 float4 per thread
        float4 a0 = *(const float4*)&A[(size_t)(rowTile + lrow) * lda + k0 + lq * 4];
        float4 a1 = *(const float4*)&A[(size_t)(rowTile + lrow + 64) * lda + k0 + lq * 4];
        // Load W tile (64x16): 1 float4 per thread
        float4 w0 = *(const float4*)&W[(size_t)(colTile + lrow) * ldw + k0 + lq * 4];

        As[lq * 4 + 0][lrow] = a0.x; As[lq * 4 + 1][lrow] = a0.y;
        As[lq * 4 + 2][lrow] = a0.z; As[lq * 4 + 3][lrow] = a0.w;
        As[lq * 4 + 0][lrow + 64] = a1.x; As[lq * 4 + 1][lrow + 64] = a1.y;
        As[lq * 4 + 2][lrow + 64] = a1.z; As[lq * 4 + 3][lrow + 64] = a1.w;
        Ws[lq * 4 + 0][lrow] = w0.x; Ws[lq * 4 + 1][lrow] = w0.y;
        Ws[lq * 4 + 2][lrow] = w0.z; Ws[lq * 4 + 3][lrow] = w0.w;
        __syncthreads();

#pragma unroll
        for (int k = 0; k < 16; ++k) {
            float4 b4 = *(const float4*)&Ws[k][c0];
            float4 x0 = *(const float4*)&As[k][r0];
            float4 x1 = *(const float4*)&As[k][r0 + 4];
            float bv[4] = {b4.x, b4.y, b4.z, b4.w};
            float av[8] = {x0.x, x0.y, x0.z, x0.w, x1.x, x1.y, x1.z, x1.w};
#pragma unroll
            for (int rr = 0; rr < 8; ++rr)
#pragma unroll
                for (int cc = 0; cc < 4; ++cc)
                    acc[rr][cc] = fmaf(av[rr], bv[cc], acc[rr][cc]);
        }
        __syncthreads();
    }

    float bb[4] = {0.f, 0.f, 0.f, 0.f};
    if (bias) {
        float4 t4 = *(const float4*)&bias[colTile + c0];
        bb[0] = t4.x; bb[1] = t4.y; bb[2] = t4.z; bb[3] = t4.w;
    }

#pragma unroll
    for (int rr = 0; rr < 8; ++rr) {
        const int row = rowTile + r0 + rr;
        float x[4];
#pragma unroll
        for (int cc = 0; cc < 4; ++cc) x[cc] = acc[rr][cc] + bb[cc];

        if constexpr (EPI == EPI_SPSIG) {
            float4 sv, gv;
            sv.x = softplus_f(x[0]); sv.y = softplus_f(x[1]);
            sv.z = softplus_f(x[2]); sv.w = softplus_f(x[3]);
            gv.x = sigmoid_f(x[0]); gv.y = sigmoid_f(x[1]);
            gv.z = sigmoid_f(x[2]); gv.w = sigmoid_f(x[3]);
            *(float4*)&C0[(size_t)row * ldc + colTile + c0] = sv;
            *(float4*)&C1[(size_t)row * ldc + colTile + c0] = gv;
        } else if constexpr (EPI == EPI_TANH) {
            float4 ov;
            ov.x = tanhf(x[0]); ov.y = tanhf(x[1]);
            ov.z = tanhf(x[2]); ov.w = tanhf(x[3]);
            *(float4*)&C0[(size_t)row * ldc + colTile + c0] = ov;
        } else if constexpr (EPI == EPI_GATE) {
            float4 g4 = *(const float4*)&G[(size_t)(row >> 3) * ldc + colTile + c0];
            float4 ov;
            ov.x = x[0] * g4.x; ov.y = x[1] * g4.y;
            ov.z = x[2] * g4.z; ov.w = x[3] * g4.w;
            *(float4*)&C0[(size_t)row * ldc + colTile + c0] = ov;
        } else {
            float4 ov; ov.x = x[0]; ov.y = x[1]; ov.z = x[2]; ov.w = x[3];
            *(float4*)&C0[(size_t)row * ldc + colTile + c0] = ov;
        }
    }
}

// Mix tangents with the level-2 signature coefficients:
// T[b,i,n] = sum_k beta[k][i] * V[b,k,n],
// beta[k][i] = +sig[D+pidx(k,i)] if k<i, -sig[D+pidx(i,k)] if k>i, 0 if k==i.
__global__ __launch_bounds__(256) void ktilde_k(
    const float* __restrict__ V, const float* __restrict__ sig,
    float* __restrict__ T, int b0)
{
    const int bl = blockIdx.x;
    const int n = threadIdx.x;
    const float* vb = V + (size_t)bl * 2048;
    float v[8];
#pragma unroll
    for (int k = 0; k < 8; ++k) v[k] = vb[k * 256 + n];
    const float* sg = sig + (size_t)(b0 + bl) * MM;
    float s2v[28];
#pragma unroll
    for (int p = 0; p < 28; ++p) s2v[p] = sg[DD + p];

#pragma unroll
    for (int i = 0; i < 8; ++i) {
        float acc = 0.f;
#pragma unroll
        for (int k = 0; k < 8; ++k) {
            if (k == i) continue;
            const int a = (k < i) ? k : i;
            const int b = (k < i) ? i : k;
            const int p = a * (15 - a) / 2 + (b - a - 1);  // triu_indices(8,k=1) order
            const float c = s2v[p];
            acc += ((k < i) ? c : -c) * v[k];
        }
        T[((size_t)bl * 8 + i) * 256 + n] = acc;
    }
}

// out[b,n] = sum_i sig[b,i]*V[b,i,n] + (1 - V[b,i,n]^2) * Oi[i][b][n]
__global__ __launch_bounds__(256) void finish_k(
    const float* __restrict__ V, const float* __restrict__ Oi,
    const float* __restrict__ sig, float* __restrict__ out, int b0, int C)
{
    const int bl = blockIdx.x;
    const int n = threadIdx.x;
    const float* sg = sig + (size_t)(b0 + bl) * MM;
    float acc = 0.f;
#pragma unroll
    for (int i = 0; i < 8; ++i) {
        float v = V[(size_t)bl * 2048 + i * 256 + n];
        float o = Oi[((size_t)i * C + bl) * 256 + n];
        acc = fmaf(sg[i], v, acc);
        acc = fmaf(1.f - v * v, o, acc);
    }
    out[(size_t)(b0 + bl) * 256 + n] = acc;
}

extern "C" void kernel_launch(void* const* d_in, const int* in_sizes, int n_in,
                              void* d_out, int out_size, void* d_ws, size_t ws_size,
                              hipStream_t stream) {
    const float* h   = (const float*)d_in[0];
    const float* sig = (const float*)d_in[1];
    const float* W1  = (const float*)d_in[2];
    const float* b1  = (const float*)d_in[3];
    const float* W2  = (const float*)d_in[4];
    const float* b2  = (const float*)d_in[5];
    const float* W3  = (const float*)d_in[6];
    const float* b3  = (const float*)d_in[7];
    const float* Wo  = (const float*)d_in[8];
    const float* bo  = (const float*)d_in[9];
    float* out = (float*)d_out;

    // Per-element workspace (floats): s/g x3 = 3072, V = 2048, T/Oi (aliased) = 2048,
    // Ua+Ub = 8192  => 15360 floats = 61440 B
    int C = BB;
    while (C > 128 && (size_t)C * 15360 * 4 > ws_size) C >>= 1;

    float* p  = (float*)d_ws;
    float* s1 = p;                    // C*512
    float* g1 = s1 + (size_t)C * 512;
    float* s2 = g1 + (size_t)C * 512;
    float* g2 = s2 + (size_t)C * 512;
    float* s3 = g2 + (size_t)C * 512;
    float* g3 = s3 + (size_t)C * 512;
    float* Vb = g3 + (size_t)C * 512;   // C*2048
    float* T  = Vb + (size_t)C * 2048;  // C*2048 (aliased with Oi)
    float* Ua = T  + (size_t)C * 2048;  // C*4096
    float* Ub = Ua + (size_t)C * 4096;  // C*4096
    float* Oi = T;                      // 8 x C x 256 (T dead after JVP layer 1)

    const dim3 blk(256);
    for (int b0 = 0; b0 < BB; b0 += C) {
        // Forward
        gemm_k<EPI_SPSIG><<<dim3(C / 128, 8, 1), blk, 0, stream>>>(
            h + (size_t)b0 * 256, 256, 0, W1, 256, 0, b1, s1, 512, 0, g1, nullptr, 256);
        gemm_k<EPI_SPSIG><<<dim3(C / 128, 8, 1), blk, 0, stream>>>(
            s1, 512, 0, W2, 512, 0, b2, s2, 512, 0, g2, nullptr, 512);
        gemm_k<EPI_SPSIG><<<dim3(C / 128, 8, 1), blk, 0, stream>>>(
            s2, 512, 0, W3, 512, 0, b3, s3, 512, 0, g3, nullptr, 512);
        gemm_k<EPI_TANH><<<dim3(C / 128, 32, 1), blk, 0, stream>>>(
            s3, 512, 0, Wo, 512, 0, bo, Vb, 2048, 0, nullptr, nullptr, 512);
        // Signature-mixed tangents
        ktilde_k<<<dim3(C), blk, 0, stream>>>(Vb, sig, T, b0);
        // JVP chain (gated)
        gemm_k<EPI_GATE><<<dim3(C * 8 / 128, 8, 1), blk, 0, stream>>>(
            T, 256, 0, W1, 256, 0, nullptr, Ua, 512, 0, nullptr, g1, 256);
        gemm_k<EPI_GATE><<<dim3(C * 8 / 128, 8, 1), blk, 0, stream>>>(
            Ua, 512, 0, W2, 512, 0, nullptr, Ub, 512, 0, nullptr, g2, 512);
        gemm_k<EPI_GATE><<<dim3(C * 8 / 128, 8, 1), blk, 0, stream>>>(
            Ub, 512, 0, W3, 512, 0, nullptr, Ua, 512, 0, nullptr, g3, 512);
        // Diagonal last-layer JVP: per-field GEMM via blockIdx.z
        gemm_k<EPI_NONE><<<dim3(C / 128, 4, 8), blk, 0, stream>>>(
            Ua, 4096, 512, Wo, 512, 256 * 512, nullptr, Oi, 256, C * 256, nullptr, nullptr, 512);
        // Final contraction
        finish_k<<<dim3(C), blk, 0, stream>>>(Vb, Oi, sig, out, b0, C);
    }
}

// Round 3
// 241.295 us; speedup vs baseline: 3.8981x; 3.8981x over previous
//
#include <hip/hip_runtime.h>
#include <hip/hip_bf16.h>
#include <math.h>

#define MM 36

typedef _Float16 f16;
typedef __attribute__((ext_vector_type(8))) _Float16 f16x8;
typedef __attribute__((ext_vector_type(4))) _Float16 f16x4;
typedef __attribute__((ext_vector_type(4))) float f32x4;

enum { EPI_NONE = 0, EPI_SPSIG = 1, EPI_TANH = 2, EPI_GATE = 3 };

__device__ __forceinline__ float softplus_f(float x) {
    return fmaxf(x, 0.f) + log1pf(__expf(-fabsf(x)));
}
__device__ __forceinline__ float sigmoid_f(float x) {
    return 1.f / (1.f + __expf(-x));
}

// async global->LDS, 16B per lane. LDS dest must be wave-uniform base + lane*16.
__device__ __forceinline__ void gl_lds16(const f16* g, f16* l) {
    __builtin_amdgcn_global_load_lds(
        (const __attribute__((address_space(1))) void*)g,
        (__attribute__((address_space(3))) void*)l, 16, 0, 0);
}

// C[row, col] = EPI( sum_k A[row*lda+k] * W[col*ldw+k] (+ bias[col]) )
// 128x128 tile, BK=32, 256 threads = 4 waves, each wave 64x64 (4x4 frags of 16x16x32 f16 MFMA).
// z-batching via aZ/wZ/cZ offsets (diag per-field GEMM).
template <int EPI>
__global__ __launch_bounds__(256, 2) void gemm16(
    const f16* __restrict__ A, int lda, long aZ,
    const f16* __restrict__ W, int ldw, long wZ,
    const float* __restrict__ bias,
    void* __restrict__ C0v, int ldc, long cZ,
    f16* __restrict__ C1,
    const f16* __restrict__ G,
    int K)
{
    __shared__ f16 As[2][128 * 32];
    __shared__ f16 Ws[2][128 * 32];

    const int t = threadIdx.x;
    const int z = blockIdx.z;
    A += (size_t)z * aZ;
    W += (size_t)z * wZ;

    const long rowTile = (long)blockIdx.x * 128;
    const long colTile = (long)blockIdx.y * 128;

    const int wave = t >> 6;
    const int lane = t & 63;
    const int wr = (wave >> 1) * 64;   // wave row origin in tile
    const int wc = (wave & 1) * 64;    // wave col origin in tile
    const int lr = lane & 15;
    const int lk = lane >> 4;          // k-group 0..3

    // staging: chunk c = t and t+256; row = c>>2, k-quad = c&3 (8 f16 = 16B each)
    const int srow = t >> 2;
    const int skq = (t & 3) * 8;
    const f16* Ag = A + (rowTile + srow) * lda + skq;
    const f16* Wg = W + (colTile + srow) * ldw + skq;
    const long lda64 = (long)lda * 64;
    const long ldw64 = (long)ldw * 64;

    f32x4 acc[4][4];
    const f32x4 zero = {0.f, 0.f, 0.f, 0.f};
#pragma unroll
    for (int m = 0; m < 4; ++m)
#pragma unroll
        for (int n = 0; n < 4; ++n) acc[m][n] = zero;

    const int nt = K >> 5;
    // prologue: stage tile 0 into buf 0
    gl_lds16(Ag, &As[0][t * 8]);
    gl_lds16(Ag + lda64, &As[0][(t + 256) * 8]);
    gl_lds16(Wg, &Ws[0][t * 8]);
    gl_lds16(Wg + ldw64, &Ws[0][(t + 256) * 8]);

    for (int ti = 0; ti < nt; ++ti) {
        const int buf = ti & 1;
        __syncthreads();  // drains vmcnt -> buf ready; also fences LDS reuse
        if (ti + 1 < nt) {
            const int k0 = (ti + 1) << 5;  // prefetch flies under the MFMA below
            gl_lds16(Ag + k0, &As[buf ^ 1][t * 8]);
            gl_lds16(Ag + k0 + lda64, &As[buf ^ 1][(t + 256) * 8]);
            gl_lds16(Wg + k0, &Ws[buf ^ 1][t * 8]);
            gl_lds16(Wg + k0 + ldw64, &Ws[buf ^ 1][(t + 256) * 8]);
        }
        f16x8 a[4], b[4];
#pragma unroll
        for (int m = 0; m < 4; ++m)
            a[m] = *(const f16x8*)&As[buf][(wr + m * 16 + lr) * 32 + lk * 8];
#pragma unroll
        for (int n = 0; n < 4; ++n)
            b[n] = *(const f16x8*)&Ws[buf][(wc + n * 16 + lr) * 32 + lk * 8];
#pragma unroll
        for (int m = 0; m < 4; ++m)
#pragma unroll
            for (int n = 0; n < 4; ++n)
                acc[m][n] = __builtin_amdgcn_mfma_f32_16x16x32_f16(a[m], b[n], acc[m][n], 0, 0, 0);
    }

    // C/D layout (m89-verified): col = lane&15, row = (lane>>4)*4 + reg
    const long row0 = rowTile + wr + lk * 4;
    const long col0 = colTile + wc + lr;

#pragma unroll
    for (int m = 0; m < 4; ++m) {
#pragma unroll
        for (int n = 0; n < 4; ++n) {
            const long col = col0 + n * 16;
            const float bb = bias ? bias[col] : 0.f;
#pragma unroll
            for (int j = 0; j < 4; ++j) {
                const long row = row0 + m * 16 + j;
                const float x = acc[m][n][j] + bb;
                if constexpr (EPI == EPI_SPSIG) {
                    f16* S = (f16*)C0v;
                    S[row * ldc + col] = (f16)softplus_f(x);
                    C1[row * ldc + col] = (f16)sigmoid_f(x);
                } else if constexpr (EPI == EPI_TANH) {
                    f16* S = (f16*)C0v;
                    S[row * ldc + col] = (f16)tanhf(x);
                } else if constexpr (EPI == EPI_GATE) {
                    f16* S = (f16*)C0v;
                    const float g = (float)G[(row >> 3) * ldc + col];
                    S[row * ldc + col] = (f16)(x * g);
                } else {
                    float* S = (float*)C0v + (size_t)z * cZ;
                    S[row * ldc + col] = x;
                }
            }
        }
    }
}

// T[b,i,n] = sum_{k<i} sig2[(k,i)] V[b,k,n] - sum_{k>i} sig2[(i,k)] V[b,k,n]
__global__ __launch_bounds__(256) void ktilde16(
    const f16* __restrict__ V, const float* __restrict__ sig,
    f16* __restrict__ T, int b0)
{
    const int bl = blockIdx.x;
    const int n = threadIdx.x;
    const f16* vb = V + (size_t)bl * 2048;
    float v[8];
#pragma unroll
    for (int k = 0; k < 8; ++k) v[k] = (float)vb[k * 256 + n];
    const float* sg = sig + (size_t)(b0 + bl) * MM;
    float s2[28];
#pragma unroll
    for (int p = 0; p < 28; ++p) s2[p] = sg[8 + p];

#pragma unroll
    for (int i = 0; i < 8; ++i) {
        float acc = 0.f;
#pragma unroll
        for (int k = 0; k < 8; ++k) {
            if (k == i) continue;
            const int a = (k < i) ? k : i;
            const int b = (k < i) ? i : k;
            const int p = a * (15 - a) / 2 + (b - a - 1);
            const float c = s2[p];
            acc += ((k < i) ? c : -c) * v[k];
        }
        T[((size_t)bl * 8 + i) * 256 + n] = (f16)acc;
    }
}

// out[b,n] = sum_i sig[b,i]*V[b,i,n] + (1 - V^2) * Oi[i][b][n]
__global__ __launch_bounds__(256) void finish16(
    const f16* __restrict__ V, const float* __restrict__ Oi,
    const float* __restrict__ sig, float* __restrict__ out, int b0, int C)
{
    const int bl = blockIdx.x;
    const int n = threadIdx.x;
    const float* sg = sig + (size_t)(b0 + bl) * MM;
    float acc = 0.f;
#pragma unroll
    for (int i = 0; i < 8; ++i) {
        const float v = (float)V[(size_t)bl * 2048 + i * 256 + n];
        const float o = Oi[((size_t)i * C + bl) * 256 + n];
        acc = fmaf(sg[i], v, acc);
        acc = fmaf(1.f - v * v, o, acc);
    }
    out[(size_t)(b0 + bl) * 256 + n] = acc;
}

__global__ __launch_bounds__(256) void cvt16(
    const float* __restrict__ x, f16* __restrict__ y, int n)
{
    const int i = (blockIdx.x * 256 + threadIdx.x) * 4;
    if (i < n) {
        const float4 v = *(const float4*)&x[i];
        f16x4 o;
        o[0] = (f16)v.x; o[1] = (f16)v.y; o[2] = (f16)v.z; o[3] = (f16)v.w;
        *(f16x4*)&y[i] = o;
    }
}

extern "C" void kernel_launch(void* const* d_in, const int* in_sizes, int n_in,
                              void* d_out, int out_size, void* d_ws, size_t ws_size,
                              hipStream_t stream) {
    const float* h   = (const float*)d_in[0];
    const float* sig = (const float*)d_in[1];
    const float* W1  = (const float*)d_in[2];
    const float* b1  = (const float*)d_in[3];
    const float* W2  = (const float*)d_in[4];
    const float* b2  = (const float*)d_in[5];
    const float* W3  = (const float*)d_in[6];
    const float* b3  = (const float*)d_in[7];
    const float* Wo  = (const float*)d_in[8];
    const float* bo  = (const float*)d_in[9];
    float* out = (float*)d_out;

    char* p = (char*)d_ws;
    f16* W1h = (f16*)p; p += (size_t)512 * 256 * 2;
    f16* W2h = (f16*)p; p += (size_t)512 * 512 * 2;
    f16* W3h = (f16*)p; p += (size_t)512 * 512 * 2;
    f16* Woh = (f16*)p; p += (size_t)2048 * 512 * 2;
    const size_t fixed = (size_t)(p - (char*)d_ws);

    // per-element chunk bytes: h16 512 + s/g 6*1024 + V 4096 + T 4096 + Ua 8192 + Ub/Oi 8192
    int C = 4096;
    while (C > 128 && fixed + (size_t)C * 31232 > ws_size) C >>= 1;

    f16* h16 = (f16*)p; p += (size_t)C * 256 * 2;
    f16* s1 = (f16*)p;  p += (size_t)C * 512 * 2;
    f16* g1 = (f16*)p;  p += (size_t)C * 512 * 2;
    f16* s2 = (f16*)p;  p += (size_t)C * 512 * 2;
    f16* g2 = (f16*)p;  p += (size_t)C * 512 * 2;
    f16* s3 = (f16*)p;  p += (size_t)C * 512 * 2;
    f16* g3 = (f16*)p;  p += (size_t)C * 512 * 2;
    f16* V  = (f16*)p;  p += (size_t)C * 2048 * 2;
    f16* T  = (f16*)p;  p += (size_t)C * 2048 * 2;
    f16* Ua = (f16*)p;  p += (size_t)C * 4096 * 2;
    f16* Ub = (f16*)p;                    // C*4096 f16 = C*8192 B
    float* Oi = (float*)Ub;               // 8 x C x 256 f32 = C*8192 B (Ub dead before diag)

    const dim3 blk(256);
    // weights f32 -> f16 (once)
    cvt16<<<dim3(512 * 256 / 1024), blk, 0, stream>>>(W1, W1h, 512 * 256);
    cvt16<<<dim3(512 * 512 / 1024), blk, 0, stream>>>(W2, W2h, 512 * 512);
    cvt16<<<dim3(512 * 512 / 1024), blk, 0, stream>>>(W3, W3h, 512 * 512);
    cvt16<<<dim3(2048 * 512 / 1024), blk, 0, stream>>>(Wo, Woh, 2048 * 512);

    for (int b0 = 0; b0 < 4096; b0 += C) {
        cvt16<<<dim3(C * 256 / 1024), blk, 0, stream>>>(h + (size_t)b0 * 256, h16, C * 256);
        // Forward MLP
        gemm16<EPI_SPSIG><<<dim3(C / 128, 4, 1), blk, 0, stream>>>(
            h16, 256, 0, W1h, 256, 0, b1, s1, 512, 0, g1, nullptr, 256);
        gemm16<EPI_SPSIG><<<dim3(C / 128, 4, 1), blk, 0, stream>>>(
            s1, 512, 0, W2h, 512, 0, b2, s2, 512, 0, g2, nullptr, 512);
        gemm16<EPI_SPSIG><<<dim3(C / 128, 4, 1), blk, 0, stream>>>(
            s2, 512, 0, W3h, 512, 0, b3, s3, 512, 0, g3, nullptr, 512);
        gemm16<EPI_TANH><<<dim3(C / 128, 16, 1), blk, 0, stream>>>(
            s3, 512, 0, Woh, 512, 0, bo, V, 2048, 0, nullptr, nullptr, 512);
        // Signature-mixed tangents
        ktilde16<<<dim3(C), blk, 0, stream>>>(V, sig, T, b0);
        // JVP chain (gated epilogues)
        gemm16<EPI_GATE><<<dim3(C / 16, 4, 1), blk, 0, stream>>>(
            T, 256, 0, W1h, 256, 0, nullptr, Ua, 512, 0, nullptr, g1, 256);
        gemm16<EPI_GATE><<<dim3(C / 16, 4, 1), blk, 0, stream>>>(
            Ua, 512, 0, W2h, 512, 0, nullptr, Ub, 512, 0, nullptr, g2, 512);
        gemm16<EPI_GATE><<<dim3(C / 16, 4, 1), blk, 0, stream>>>(
            Ub, 512, 0, W3h, 512, 0, nullptr, Ua, 512, 0, nullptr, g3, 512);
        // Per-field diagonal last-layer JVP (z = field)
        gemm16<EPI_NONE><<<dim3(C / 128, 2, 8), blk, 0, stream>>>(
            Ua, 4096, 512, Woh, 512, (long)256 * 512, nullptr, Oi, 256, (long)C * 256,
            nullptr, nullptr, 512);
        // Final contraction
        finish16<<<dim3(C), blk, 0, stream>>>(V, Oi, sig, out, b0, C);
    }
}

// Round 5
// 211.501 us; speedup vs baseline: 4.4472x; 1.1409x over previous
//
#include <hip/hip_runtime.h>
#include <hip/hip_bf16.h>
#include <math.h>

#define MM 36

typedef _Float16 f16;
typedef __attribute__((ext_vector_type(8))) _Float16 f16x8;
typedef __attribute__((ext_vector_type(4))) _Float16 f16x4;
typedef __attribute__((ext_vector_type(4))) float f32x4;

enum { EPI_NONE = 0, EPI_SPSIG = 1, EPI_TANH = 2, EPI_GATE = 3 };

__device__ __forceinline__ float softplus_f(float x) {
    return fmaxf(x, 0.f) + log1pf(__expf(-fabsf(x)));
}
__device__ __forceinline__ float sigmoid_f(float x) {
    return 1.f / (1.f + __expf(-x));
}

// async global->LDS, 16B per lane. LDS dest must be wave-uniform base + lane*16.
__device__ __forceinline__ void gl_lds16(const f16* g, f16* l) {
    __builtin_amdgcn_global_load_lds(
        (const __attribute__((address_space(1))) void*)g,
        (__attribute__((address_space(3))) void*)l, 16, 0, 0);
}

// C[row, col] = EPI( sum_k A[row*lda+k] * W[col*ldw+k] (+ bias[col]) )
// BM x 128 tile, BK=32, 256 threads = 4 waves.
//  BM=128: wave grid 2x2, wave tile 64x64 (acc 4x4)
//  BM=64 : wave grid 1x4, wave tile 64x32 (acc 4x2)
// grid: x = col tiles (power of 2, log2 = cshift), y = row tiles, z = batch (diag).
// XCD-chunked bijective remap (m204) over the (x,y) plane for L2 locality.
template <int EPI, int BM>
__global__ __launch_bounds__(256, 3) void gemm16(
    const f16* __restrict__ A, int lda, long aZ,
    const f16* __restrict__ W, int ldw, long wZ,
    const float* __restrict__ bias,
    void* __restrict__ C0v, int ldc, long cZ,
    f16* __restrict__ C1,
    const f16* __restrict__ G,
    int K, int cshift)
{
    constexpr int WCOLS = (BM == 128) ? 2 : 4;  // waves along N
    constexpr int FN    = (BM == 128) ? 4 : 2;  // 16-wide frags per wave along N

    __shared__ f16 As[2][BM * 32];
    __shared__ f16 Ws[2][128 * 32];

    const int t = threadIdx.x;
    const int z = blockIdx.z;
    A += (size_t)z * aZ;
    W += (size_t)z * wZ;

    // bijective XCD-chunked remap: HW round-robins orig%8 across XCDs, so giving
    // XCD k the contiguous work chunk [base_k, base_k+q) makes neighboring row
    // tiles (which share A/W panels) land in one XCD's L2.
    const int nxy = gridDim.x * gridDim.y;
    const int orig = blockIdx.x + gridDim.x * blockIdx.y;
    const int q = nxy >> 3, r = nxy & 7;
    const int xcd = orig & 7, idx = orig >> 3;
    const int nid = (xcd < r ? xcd * (q + 1) : r * (q + 1) + (xcd - r) * q) + idx;
    const long rowTile = (long)(nid >> cshift) * BM;
    const long colTile = (long)(nid & ((1 << cshift) - 1)) * 128;

    const int wave = t >> 6;
    const int lane = t & 63;
    const int wr = (wave / WCOLS) * 64;
    const int wc = (wave % WCOLS) * (FN * 16);
    const int lr = lane & 15;
    const int lk = lane >> 4;          // k-group 0..3

    // staging: chunk c -> row c>>2, 16B quad c&3
    const int srow = t >> 2;
    const int skq = (t & 3) * 8;
    const f16* Ag = A + (rowTile + srow) * lda + skq;
    const f16* Wg = W + (colTile + srow) * ldw + skq;
    const long lda64 = (long)lda * 64;
    const long ldw64 = (long)ldw * 64;

    f32x4 acc[4][FN];
    const f32x4 zero = {0.f, 0.f, 0.f, 0.f};
#pragma unroll
    for (int m = 0; m < 4; ++m)
#pragma unroll
        for (int n = 0; n < FN; ++n) acc[m][n] = zero;

    const int nt = K >> 5;
    // prologue: stage tile 0 into buf 0
    gl_lds16(Ag, &As[0][t * 8]);
    if constexpr (BM == 128) gl_lds16(Ag + lda64, &As[0][(t + 256) * 8]);
    gl_lds16(Wg, &Ws[0][t * 8]);
    gl_lds16(Wg + ldw64, &Ws[0][(t + 256) * 8]);

    for (int ti = 0; ti < nt; ++ti) {
        const int buf = ti & 1;
        __syncthreads();  // drains vmcnt -> buf ready; also fences LDS reuse
        if (ti + 1 < nt) {
            const int k0 = (ti + 1) << 5;  // prefetch flies under the MFMA below
            gl_lds16(Ag + k0, &As[buf ^ 1][t * 8]);
            if constexpr (BM == 128) gl_lds16(Ag + k0 + lda64, &As[buf ^ 1][(t + 256) * 8]);
            gl_lds16(Wg + k0, &Ws[buf ^ 1][t * 8]);
            gl_lds16(Wg + k0 + ldw64, &Ws[buf ^ 1][(t + 256) * 8]);
        }
        f16x8 a[4], b[FN];
#pragma unroll
        for (int m = 0; m < 4; ++m)
            a[m] = *(const f16x8*)&As[buf][(wr + m * 16 + lr) * 32 + lk * 8];
#pragma unroll
        for (int n = 0; n < FN; ++n)
            b[n] = *(const f16x8*)&Ws[buf][(wc + n * 16 + lr) * 32 + lk * 8];
#pragma unroll
        for (int m = 0; m < 4; ++m)
#pragma unroll
            for (int n = 0; n < FN; ++n)
                acc[m][n] = __builtin_amdgcn_mfma_f32_16x16x32_f16(a[m], b[n], acc[m][n], 0, 0, 0);
    }

    // C/D layout (m89-verified): col = lane&15, row = (lane>>4)*4 + reg
    const long row0 = rowTile + wr + lk * 4;
    const long col0 = colTile + wc + lr;

#pragma unroll
    for (int m = 0; m < 4; ++m) {
#pragma unroll
        for (int n = 0; n < FN; ++n) {
            const long col = col0 + n * 16;
            const float bb = bias ? bias[col] : 0.f;
#pragma unroll
            for (int j = 0; j < 4; ++j) {
                const long row = row0 + m * 16 + j;
                const float x = acc[m][n][j] + bb;
                if constexpr (EPI == EPI_SPSIG) {
                    f16* S = (f16*)C0v;
                    S[row * ldc + col] = (f16)softplus_f(x);
                    C1[row * ldc + col] = (f16)sigmoid_f(x);
                } else if constexpr (EPI == EPI_TANH) {
                    f16* S = (f16*)C0v;
                    S[row * ldc + col] = (f16)tanhf(x);
                } else if constexpr (EPI == EPI_GATE) {
                    f16* S = (f16*)C0v;
                    const float g = (float)G[(row >> 3) * ldc + col];
                    S[row * ldc + col] = (f16)(x * g);
                } else {
                    float* S = (float*)C0v + (size_t)z * cZ;
                    S[row * ldc + col] = x;
                }
            }
        }
    }
}

// T[b,i,n] = sum_{k<i} sig2[(k,i)] V[b,k,n] - sum_{k>i} sig2[(i,k)] V[b,k,n]
__global__ __launch_bounds__(256) void ktilde16(
    const f16* __restrict__ V, const float* __restrict__ sig,
    f16* __restrict__ T, int b0)
{
    const int bl = blockIdx.x;
    const int n = threadIdx.x;
    const f16* vb = V + (size_t)bl * 2048;
    float v[8];
#pragma unroll
    for (int k = 0; k < 8; ++k) v[k] = (float)vb[k * 256 + n];
    const float* sg = sig + (size_t)(b0 + bl) * MM;
    float s2[28];
#pragma unroll
    for (int p = 0; p < 28; ++p) s2[p] = sg[8 + p];

#pragma unroll
    for (int i = 0; i < 8; ++i) {
        float acc = 0.f;
#pragma unroll
        for (int k = 0; k < 8; ++k) {
            if (k == i) continue;
            const int a = (k < i) ? k : i;
            const int b = (k < i) ? i : k;
            const int p = a * (15 - a) / 2 + (b - a - 1);
            const float c = s2[p];
            acc += ((k < i) ? c : -c) * v[k];
        }
        T[((size_t)bl * 8 + i) * 256 + n] = (f16)acc;
    }
}

// out[b,n] = sum_i sig[b,i]*V[b,i,n] + (1 - V^2) * Oi[i][b][n]
__global__ __launch_bounds__(256) void finish16(
    const f16* __restrict__ V, const float* __restrict__ Oi,
    const float* __restrict__ sig, float* __restrict__ out, int b0, int C)
{
    const int bl = blockIdx.x;
    const int n = threadIdx.x;
    const float* sg = sig + (size_t)(b0 + bl) * MM;
    float acc = 0.f;
#pragma unroll
    for (int i = 0; i < 8; ++i) {
        const float v = (float)V[(size_t)bl * 2048 + i * 256 + n];
        const float o = Oi[((size_t)i * C + bl) * 256 + n];
        acc = fmaf(sg[i], v, acc);
        acc = fmaf(1.f - v * v, o, acc);
    }
    out[(size_t)(b0 + bl) * 256 + n] = acc;
}

__global__ __launch_bounds__(256) void cvt16(
    const float* __restrict__ x, f16* __restrict__ y, int n)
{
    const int i = (blockIdx.x * 256 + threadIdx.x) * 4;
    if (i < n) {
        const float4 v = *(const float4*)&x[i];
        f16x4 o;
        o[0] = (f16)v.x; o[1] = (f16)v.y; o[2] = (f16)v.z; o[3] = (f16)v.w;
        *(f16x4*)&y[i] = o;
    }
}

extern "C" void kernel_launch(void* const* d_in, const int* in_sizes, int n_in,
                              void* d_out, int out_size, void* d_ws, size_t ws_size,
                              hipStream_t stream) {
    const float* h   = (const float*)d_in[0];
    const float* sig = (const float*)d_in[1];
    const float* W1  = (const float*)d_in[2];
    const float* b1  = (const float*)d_in[3];
    const float* W2  = (const float*)d_in[4];
    const float* b2  = (const float*)d_in[5];
    const float* W3  = (const float*)d_in[6];
    const float* b3  = (const float*)d_in[7];
    const float* Wo  = (const float*)d_in[8];
    const float* bo  = (const float*)d_in[9];
    float* out = (float*)d_out;

    char* p = (char*)d_ws;
    f16* W1h = (f16*)p; p += (size_t)512 * 256 * 2;
    f16* W2h = (f16*)p; p += (size_t)512 * 512 * 2;
    f16* W3h = (f16*)p; p += (size_t)512 * 512 * 2;
    f16* Woh = (f16*)p; p += (size_t)2048 * 512 * 2;
    const size_t fixed = (size_t)(p - (char*)d_ws);

    // per-element chunk bytes: h16 512 + s/g 6*1024 + V 4096 + T 4096 + Ua 8192 + Ub/Oi 8192
    int C = 4096;
    while (C > 128 && fixed + (size_t)C * 31232 > ws_size) C >>= 1;

    f16* h16 = (f16*)p; p += (size_t)C * 256 * 2;
    f16* s1 = (f16*)p;  p += (size_t)C * 512 * 2;
    f16* g1 = (f16*)p;  p += (size_t)C * 512 * 2;
    f16* s2 = (f16*)p;  p += (size_t)C * 512 * 2;
    f16* g2 = (f16*)p;  p += (size_t)C * 512 * 2;
    f16* s3 = (f16*)p;  p += (size_t)C * 512 * 2;
    f16* g3 = (f16*)p;  p += (size_t)C * 512 * 2;
    f16* V  = (f16*)p;  p += (size_t)C * 2048 * 2;
    f16* T  = (f16*)p;  p += (size_t)C * 2048 * 2;
    f16* Ua = (f16*)p;  p += (size_t)C * 4096 * 2;
    f16* Ub = (f16*)p;                    // C*4096 f16 = C*8192 B
    float* Oi = (float*)Ub;               // 8 x C x 256 f32 = C*8192 B (Ub dead before diag)

    const dim3 blk(256);
    // weights f32 -> f16 (once)
    cvt16<<<dim3(512 * 256 / 1024), blk, 0, stream>>>(W1, W1h, 512 * 256);
    cvt16<<<dim3(512 * 512 / 1024), blk, 0, stream>>>(W2, W2h, 512 * 512);
    cvt16<<<dim3(512 * 512 / 1024), blk, 0, stream>>>(W3, W3h, 512 * 512);
    cvt16<<<dim3(2048 * 512 / 1024), blk, 0, stream>>>(Wo, Woh, 2048 * 512);

    for (int b0 = 0; b0 < 4096; b0 += C) {
        cvt16<<<dim3(C * 256 / 1024), blk, 0, stream>>>(h + (size_t)b0 * 256, h16, C * 256);
        // Forward MLP (BM=64: 2x the block count for the half-size batch dim)
        gemm16<EPI_SPSIG, 64><<<dim3(4, C / 64), blk, 0, stream>>>(
            h16, 256, 0, W1h, 256, 0, b1, s1, 512, 0, g1, nullptr, 256, 2);
        gemm16<EPI_SPSIG, 64><<<dim3(4, C / 64), blk, 0, stream>>>(
            s1, 512, 0, W2h, 512, 0, b2, s2, 512, 0, g2, nullptr, 512, 2);
        gemm16<EPI_SPSIG, 64><<<dim3(4, C / 64), blk, 0, stream>>>(
            s2, 512, 0, W3h, 512, 0, b3, s3, 512, 0, g3, nullptr, 512, 2);
        gemm16<EPI_TANH, 128><<<dim3(16, C / 128), blk, 0, stream>>>(
            s3, 512, 0, Woh, 512, 0, bo, V, 2048, 0, nullptr, nullptr, 512, 4);
        // Signature-mixed tangents
        ktilde16<<<dim3(C), blk, 0, stream>>>(V, sig, T, b0);
        // JVP chain (gated epilogues); rows = 8*C
        gemm16<EPI_GATE, 128><<<dim3(4, C / 16), blk, 0, stream>>>(
            T, 256, 0, W1h, 256, 0, nullptr, Ua, 512, 0, nullptr, g1, 256, 2);
        gemm16<EPI_GATE, 128><<<dim3(4, C / 16), blk, 0, stream>>>(
            Ua, 512, 0, W2h, 512, 0, nullptr, Ub, 512, 0, nullptr, g2, 512, 2);
        gemm16<EPI_GATE, 128><<<dim3(4, C / 16), blk, 0, stream>>>(
            Ub, 512, 0, W3h, 512, 0, nullptr, Ua, 512, 0, nullptr, g3, 512, 2);
        // Per-field diagonal last-layer JVP (z = field)
        gemm16<EPI_NONE, 128><<<dim3(2, C / 128, 8), blk, 0, stream>>>(
            Ua, 4096, 512, Woh, 512, (long)256 * 512, nullptr, Oi, 256, (long)C * 256,
            nullptr, nullptr, 512, 1);
        // Final contraction
        finish16<<<dim3(C), blk, 0, stream>>>(V, Oi, sig, out, b0, C);
    }
}

// Round 7
// 186.486 us; speedup vs baseline: 5.0437x; 1.1341x over previous
//
#include <hip/hip_runtime.h>
#include <hip/hip_bf16.h>
#include <math.h>

#define MM 36

typedef _Float16 f16;
typedef __attribute__((ext_vector_type(8))) _Float16 f16x8;
typedef __attribute__((ext_vector_type(4))) _Float16 f16x4;
typedef __attribute__((ext_vector_type(4))) float f32x4;

enum { EPI_NONE = 0, EPI_SPSIG = 1, EPI_TANH = 2, EPI_GATE = 3 };

// async global->LDS, 16B per lane. LDS dest must be wave-uniform base + lane*16.
__device__ __forceinline__ void gl_lds16(const f16* g, f16* l) {
    __builtin_amdgcn_global_load_lds(
        (const __attribute__((address_space(1))) void*)g,
        (__attribute__((address_space(3))) void*)l, 16, 0, 0);
}

// C[row, col] = EPI( sum_k A[row*lda+k] * W[col*ldw+k] (+ bias[col]) )
// BM x 128 tile, BK=32, 256 threads = 4 waves.
//  BM=128: wave grid 2x2, wave tile 64x64 (acc 4x4)
//  BM=64 : wave grid 1x4, wave tile 64x32 (acc 4x2)
// grid: x = col tiles (power of 2, log2 = cshift), y = row tiles, z = batch (diag).
// XCD-chunked bijective remap (m204) over the (x,y) plane for L2 locality.
template <int EPI, int BM>
__global__ __launch_bounds__(256, 3) void gemm16(
    const f16* __restrict__ A, int lda, long aZ,
    const f16* __restrict__ W, int ldw, long wZ,
    const float* __restrict__ bias,
    void* __restrict__ C0v, int ldc, long cZ,
    f16* __restrict__ C1,
    const f16* __restrict__ G,
    int K, int cshift)
{
    constexpr int WCOLS = (BM == 128) ? 2 : 4;  // waves along N
    constexpr int FN    = (BM == 128) ? 4 : 2;  // 16-wide frags per wave along N

    __shared__ f16 As[2][BM * 32];
    __shared__ f16 Ws[2][128 * 32];

    const int t = threadIdx.x;
    const int z = blockIdx.z;
    A += (size_t)z * aZ;
    W += (size_t)z * wZ;

    // bijective XCD-chunked remap: HW round-robins orig%8 across XCDs, so giving
    // XCD k the contiguous work chunk [base_k, base_k+q) makes neighboring row
    // tiles (which share A/W panels) land in one XCD's L2.
    const int nxy = gridDim.x * gridDim.y;
    const int orig = blockIdx.x + gridDim.x * blockIdx.y;
    const int q = nxy >> 3, r = nxy & 7;
    const int xcd = orig & 7, idx = orig >> 3;
    const int nid = (xcd < r ? xcd * (q + 1) : r * (q + 1) + (xcd - r) * q) + idx;
    const long rowTile = (long)(nid >> cshift) * BM;
    const long colTile = (long)(nid & ((1 << cshift) - 1)) * 128;

    const int wave = t >> 6;
    const int lane = t & 63;
    const int wr = (wave / WCOLS) * 64;
    const int wc = (wave % WCOLS) * (FN * 16);
    const int lr = lane & 15;
    const int lk = lane >> 4;          // k-group 0..3

    // staging: chunk c -> row c>>2, 16B quad c&3
    const int srow = t >> 2;
    const int skq = (t & 3) * 8;
    const f16* Ag = A + (rowTile + srow) * lda + skq;
    const f16* Wg = W + (colTile + srow) * ldw + skq;
    const long lda64 = (long)lda * 64;
    const long ldw64 = (long)ldw * 64;

    f32x4 acc[4][FN];
    const f32x4 zero = {0.f, 0.f, 0.f, 0.f};
#pragma unroll
    for (int m = 0; m < 4; ++m)
#pragma unroll
        for (int n = 0; n < FN; ++n) acc[m][n] = zero;

    const int nt = K >> 5;
    // prologue: stage tile 0 into buf 0
    gl_lds16(Ag, &As[0][t * 8]);
    if constexpr (BM == 128) gl_lds16(Ag + lda64, &As[0][(t + 256) * 8]);
    gl_lds16(Wg, &Ws[0][t * 8]);
    gl_lds16(Wg + ldw64, &Ws[0][(t + 256) * 8]);

    for (int ti = 0; ti < nt; ++ti) {
        const int buf = ti & 1;
        __syncthreads();  // drains vmcnt -> buf ready; also fences LDS reuse
        if (ti + 1 < nt) {
            const int k0 = (ti + 1) << 5;  // prefetch flies under the MFMA below
            gl_lds16(Ag + k0, &As[buf ^ 1][t * 8]);
            if constexpr (BM == 128) gl_lds16(Ag + k0 + lda64, &As[buf ^ 1][(t + 256) * 8]);
            gl_lds16(Wg + k0, &Ws[buf ^ 1][t * 8]);
            gl_lds16(Wg + k0 + ldw64, &Ws[buf ^ 1][(t + 256) * 8]);
        }
        f16x8 a[4], b[FN];
#pragma unroll
        for (int m = 0; m < 4; ++m)
            a[m] = *(const f16x8*)&As[buf][(wr + m * 16 + lr) * 32 + lk * 8];
#pragma unroll
        for (int n = 0; n < FN; ++n)
            b[n] = *(const f16x8*)&Ws[buf][(wc + n * 16 + lr) * 32 + lk * 8];
#pragma unroll
        for (int m = 0; m < 4; ++m)
#pragma unroll
            for (int n = 0; n < FN; ++n)
                acc[m][n] = __builtin_amdgcn_mfma_f32_16x16x32_f16(a[m], b[n], acc[m][n], 0, 0, 0);
    }

    // C/D layout (m89-verified): col = lane&15, row = (lane>>4)*4 + reg
    const long row0 = rowTile + wr + lk * 4;
    const long col0 = colTile + wc + lr;

#pragma unroll
    for (int m = 0; m < 4; ++m) {
#pragma unroll
        for (int n = 0; n < FN; ++n) {
            const long col = col0 + n * 16;
            const float bb = bias ? bias[col] : 0.f;
#pragma unroll
            for (int j = 0; j < 4; ++j) {
                const long row = row0 + m * 16 + j;
                const float x = acc[m][n][j] + bb;
                if constexpr (EPI == EPI_SPSIG) {
                    // shared-exp softplus + sigmoid: 1 exp + 1 log + 1 rcp
                    const float e = __expf(-fabsf(x));
                    const float r1 = __builtin_amdgcn_rcpf(1.f + e);
                    const float sp = fmaxf(x, 0.f) + __logf(1.f + e);
                    const float sg = (x >= 0.f) ? r1 : e * r1;
                    f16* S = (f16*)C0v;
                    S[row * ldc + col] = (f16)sp;
                    C1[row * ldc + col] = (f16)sg;
                } else if constexpr (EPI == EPI_TANH) {
                    // fast tanh: 1 - 2/(e^{2x}+1); exact at +/-inf, ~1e-5 rel err
                    const float e2 = __expf(2.f * x);
                    const float th = 1.f - 2.f * __builtin_amdgcn_rcpf(e2 + 1.f);
                    f16* S = (f16*)C0v;
                    S[row * ldc + col] = (f16)th;
                } else if constexpr (EPI == EPI_GATE) {
                    f16* S = (f16*)C0v;
                    const float g = (float)G[(row >> 3) * ldc + col];
                    S[row * ldc + col] = (f16)(x * g);
                } else {
                    float* S = (float*)C0v + (size_t)z * cZ;
                    S[row * ldc + col] = x;
                }
            }
        }
    }
}

// T[b,i,n] = sum_{k<i} sig2[(k,i)] V[b,k,n] - sum_{k>i} sig2[(i,k)] V[b,k,n]
// 4 batch rows per block; each thread handles 4 consecutive n (f16x4).
__global__ __launch_bounds__(256) void ktilde16(
    const f16* __restrict__ V, const float* __restrict__ sig,
    f16* __restrict__ T, int b0)
{
    const int bl = blockIdx.x * 4 + (threadIdx.x >> 6);
    const int n0 = (threadIdx.x & 63) * 4;
    const f16* vb = V + (size_t)bl * 2048 + n0;
    float v[8][4];
#pragma unroll
    for (int k = 0; k < 8; ++k) {
        const f16x4 x = *(const f16x4*)&vb[k * 256];
#pragma unroll
        for (int j = 0; j < 4; ++j) v[k][j] = (float)x[j];
    }
    const float* sg = sig + (size_t)(b0 + bl) * MM + 8;
    float s2[28];
#pragma unroll
    for (int p = 0; p < 28; ++p) s2[p] = sg[p];

    f16* tb = T + (size_t)bl * 2048 + n0;
#pragma unroll
    for (int i = 0; i < 8; ++i) {
        float a0 = 0.f, a1 = 0.f, a2 = 0.f, a3 = 0.f;
#pragma unroll
        for (int k = 0; k < 8; ++k) {
            if (k == i) continue;
            const int a = (k < i) ? k : i;
            const int b = (k < i) ? i : k;
            const int p = a * (15 - a) / 2 + (b - a - 1);
            const float c = (k < i) ? s2[p] : -s2[p];
            a0 = fmaf(c, v[k][0], a0); a1 = fmaf(c, v[k][1], a1);
            a2 = fmaf(c, v[k][2], a2); a3 = fmaf(c, v[k][3], a3);
        }
        f16x4 o;
        o[0] = (f16)a0; o[1] = (f16)a1; o[2] = (f16)a2; o[3] = (f16)a3;
        *(f16x4*)&tb[i * 256] = o;
    }
}

// out[b,n] = sum_i sig[b,i]*V[b,i,n] + (1 - V^2) * Oi[i][b][n]
// 4 batch rows per block; each thread handles 4 consecutive n.
__global__ __launch_bounds__(256) void finish16(
    const f16* __restrict__ V, const float* __restrict__ Oi,
    const float* __restrict__ sig, float* __restrict__ out, int b0, int C)
{
    const int bl = blockIdx.x * 4 + (threadIdx.x >> 6);
    const int n0 = (threadIdx.x & 63) * 4;
    const float* sg = sig + (size_t)(b0 + bl) * MM;
    float a0 = 0.f, a1 = 0.f, a2 = 0.f, a3 = 0.f;
#pragma unroll
    for (int i = 0; i < 8; ++i) {
        const f16x4 vv = *(const f16x4*)&V[(size_t)bl * 2048 + i * 256 + n0];
        const float4 o = *(const float4*)&Oi[((size_t)i * C + bl) * 256 + n0];
        const float s = sg[i];
        const float v0 = (float)vv[0], v1 = (float)vv[1];
        const float v2 = (float)vv[2], v3 = (float)vv[3];
        a0 = fmaf(s, v0, a0); a0 = fmaf(1.f - v0 * v0, o.x, a0);
        a1 = fmaf(s, v1, a1); a1 = fmaf(1.f - v1 * v1, o.y, a1);
        a2 = fmaf(s, v2, a2); a2 = fmaf(1.f - v2 * v2, o.z, a2);
        a3 = fmaf(s, v3, a3); a3 = fmaf(1.f - v3 * v3, o.w, a3);
    }
    float4 ov; ov.x = a0; ov.y = a1; ov.z = a2; ov.w = a3;
    *(float4*)&out[(size_t)(b0 + bl) * 256 + n0] = ov;
}

__global__ __launch_bounds__(256) void cvt16(
    const float* __restrict__ x, f16* __restrict__ y, int n)
{
    const int i = (blockIdx.x * 256 + threadIdx.x) * 4;
    if (i < n) {
        const float4 v = *(const float4*)&x[i];
        f16x4 o;
        o[0] = (f16)v.x; o[1] = (f16)v.y; o[2] = (f16)v.z; o[3] = (f16)v.w;
        *(f16x4*)&y[i] = o;
    }
}

extern "C" void kernel_launch(void* const* d_in, const int* in_sizes, int n_in,
                              void* d_out, int out_size, void* d_ws, size_t ws_size,
                              hipStream_t stream) {
    const float* h   = (const float*)d_in[0];
    const float* sig = (const float*)d_in[1];
    const float* W1  = (const float*)d_in[2];
    const float* b1  = (const float*)d_in[3];
    const float* W2  = (const float*)d_in[4];
    const float* b2  = (const float*)d_in[5];
    const float* W3  = (const float*)d_in[6];
    const float* b3  = (const float*)d_in[7];
    const float* Wo  = (const float*)d_in[8];
    const float* bo  = (const float*)d_in[9];
    float* out = (float*)d_out;

    char* p = (char*)d_ws;
    f16* W1h = (f16*)p; p += (size_t)512 * 256 * 2;
    f16* W2h = (f16*)p; p += (size_t)512 * 512 * 2;
    f16* W3h = (f16*)p; p += (size_t)512 * 512 * 2;
    f16* Woh = (f16*)p; p += (size_t)2048 * 512 * 2;
    const size_t fixed = (size_t)(p - (char*)d_ws);

    // per-element chunk bytes: h16 512 + s/g 6*1024 + V 4096 + T 4096 + Ua 8192 + Ub/Oi 8192
    int C = 4096;
    while (C > 128 && fixed + (size_t)C * 31232 > ws_size) C >>= 1;

    f16* h16 = (f16*)p; p += (size_t)C * 256 * 2;
    f16* s1 = (f16*)p;  p += (size_t)C * 512 * 2;
    f16* g1 = (f16*)p;  p += (size_t)C * 512 * 2;
    f16* s2 = (f16*)p;  p += (size_t)C * 512 * 2;
    f16* g2 = (f16*)p;  p += (size_t)C * 512 * 2;
    f16* s3 = (f16*)p;  p += (size_t)C * 512 * 2;
    f16* g3 = (f16*)p;  p += (size_t)C * 512 * 2;
    f16* V  = (f16*)p;  p += (size_t)C * 2048 * 2;
    f16* T  = (f16*)p;  p += (size_t)C * 2048 * 2;
    f16* Ua = (f16*)p;  p += (size_t)C * 4096 * 2;
    f16* Ub = (f16*)p;                    // C*4096 f16 = C*8192 B
    float* Oi = (float*)Ub;               // 8 x C x 256 f32 = C*8192 B (Ub dead before diag)

    const dim3 blk(256);
    // weights f32 -> f16 (once)
    cvt16<<<dim3(512 * 256 / 1024), blk, 0, stream>>>(W1, W1h, 512 * 256);
    cvt16<<<dim3(512 * 512 / 1024), blk, 0, stream>>>(W2, W2h, 512 * 512);
    cvt16<<<dim3(512 * 512 / 1024), blk, 0, stream>>>(W3, W3h, 512 * 512);
    cvt16<<<dim3(2048 * 512 / 1024), blk, 0, stream>>>(Wo, Woh, 2048 * 512);

    for (int b0 = 0; b0 < 4096; b0 += C) {
        cvt16<<<dim3(C * 256 / 1024), blk, 0, stream>>>(h + (size_t)b0 * 256, h16, C * 256);
        // Forward MLP (BM=64: 2x the block count for the half-size batch dim)
        gemm16<EPI_SPSIG, 64><<<dim3(4, C / 64), blk, 0, stream>>>(
            h16, 256, 0, W1h, 256, 0, b1, s1, 512, 0, g1, nullptr, 256, 2);
        gemm16<EPI_SPSIG, 64><<<dim3(4, C / 64), blk, 0, stream>>>(
            s1, 512, 0, W2h, 512, 0, b2, s2, 512, 0, g2, nullptr, 512, 2);
        gemm16<EPI_SPSIG, 64><<<dim3(4, C / 64), blk, 0, stream>>>(
            s2, 512, 0, W3h, 512, 0, b3, s3, 512, 0, g3, nullptr, 512, 2);
        gemm16<EPI_TANH, 128><<<dim3(16, C / 128), blk, 0, stream>>>(
            s3, 512, 0, Woh, 512, 0, bo, V, 2048, 0, nullptr, nullptr, 512, 4);
        // Signature-mixed tangents
        ktilde16<<<dim3(C / 4), blk, 0, stream>>>(V, sig, T, b0);
        // JVP chain (gated epilogues); rows = 8*C
        gemm16<EPI_GATE, 128><<<dim3(4, C / 16), blk, 0, stream>>>(
            T, 256, 0, W1h, 256, 0, nullptr, Ua, 512, 0, nullptr, g1, 256, 2);
        gemm16<EPI_GATE, 128><<<dim3(4, C / 16), blk, 0, stream>>>(
            Ua, 512, 0, W2h, 512, 0, nullptr, Ub, 512, 0, nullptr, g2, 512, 2);
        gemm16<EPI_GATE, 128><<<dim3(4, C / 16), blk, 0, stream>>>(
            Ub, 512, 0, W3h, 512, 0, nullptr, Ua, 512, 0, nullptr, g3, 512, 2);
        // Per-field diagonal last-layer JVP (z = field)
        gemm16<EPI_NONE, 128><<<dim3(2, C / 128, 8), blk, 0, stream>>>(
            Ua, 4096, 512, Woh, 512, (long)256 * 512, nullptr, Oi, 256, (long)C * 256,
            nullptr, nullptr, 512, 1);
        // Final contraction
        finish16<<<dim3(C / 4), blk, 0, stream>>>(V, Oi, sig, out, b0, C);
    }
}